// Round 5
// baseline (156.048 us; speedup 1.0000x reference)
//
#include <hip/hip_runtime.h>

#define NV 40962
#define NF 81920
#define BSZ 8
#define CIN 32
#define COUT 64
#define BC 256   // BSZ*CIN

typedef unsigned short u16;
typedef float    f32x4 __attribute__((ext_vector_type(4)));
typedef _Float16 f16x8 __attribute__((ext_vector_type(8)));
typedef unsigned short u16x4 __attribute__((ext_vector_type(4)));
typedef unsigned short u16x8 __attribute__((ext_vector_type(8)));

__device__ __forceinline__ float bf2f(u16 h) {
    return __uint_as_float(((unsigned int)h) << 16);
}
__device__ __forceinline__ u16 f2bf(float f) {
    unsigned int u = __float_as_uint(f);
    unsigned int r = (u + 0x7fffu + ((u >> 16) & 1u)) >> 16;
    return (u16)r;
}

// ---------------- Kernel A: transpose input (256 x NV f32) -> xt (NV x 256 bf16)
__global__ __launch_bounds__(256) void k_transpose(const float* __restrict__ in,
                                                   u16* __restrict__ xt) {
    __shared__ float tile[32][33];   // [bc_local][v_local]
    int c0 = blockIdx.x * 32;   // v-dim tile start
    int r0 = blockIdx.y * 32;   // bc-dim tile start
    int tx = threadIdx.x & 31;
    int ty = threadIdx.x >> 5;  // 0..7
    #pragma unroll
    for (int i = 0; i < 32; i += 8) {
        int cc = c0 + tx;
        float v = 0.f;
        if (cc < NV) v = in[(size_t)(r0 + ty + i) * NV + cc];
        tile[ty + i][tx] = v;
    }
    __syncthreads();
    int t = threadIdx.x;
    #pragma unroll
    for (int e = t; e < 512; e += 256) {
        int vl = e >> 4;          // 0..31 (v_local)
        int p  = e & 15;          // channel pair
        int v  = c0 + vl;
        if (v < NV) {
            ushort2 val;
            val.x = f2bf(tile[p * 2][vl]);
            val.y = f2bf(tile[p * 2 + 1][vl]);
            *(ushort2*)&xt[(size_t)v * BC + r0 + p * 2] = val;
        }
    }
}

// ---------------- Kernel B: 8 faces/block, 2 faces/wave (deep MLP),
// G/EW/NS staged through LDS once per block; ushort4 gathers (full row/wave-load).
// gfi layout: [f][C2][4] = {ew_lo, ew_hi, ns_lo, ns_hi} per channel-pair.
__global__ __launch_bounds__(256) void k_faces(const u16* __restrict__ xt,
                                               const int* __restrict__ Gc,
                                               const float* __restrict__ Gv,
                                               const float* __restrict__ EW,
                                               const float* __restrict__ NS,
                                               u16* __restrict__ gfi) {
    __shared__ int   sGc[3][24];
    __shared__ float sGv[3][24];
    __shared__ float sEW[24];
    __shared__ float sNS[24];
    int t  = threadIdx.x;
    int f0 = blockIdx.x * 8;              // NF/8 = 10240 blocks, no tail

    if (t < 24) {
        #pragma unroll
        for (int d = 0; d < 3; ++d) {
            sGc[d][t] = Gc[3 * (d * NF + f0) + t];
            sGv[d][t] = Gv[3 * (d * NF + f0) + t];
        }
    } else if (t >= 32 && t < 56) {
        sEW[t - 32] = EW[f0 * 3 + (t - 32)];
        sNS[t - 32] = NS[f0 * 3 + (t - 32)];
    }
    __syncthreads();

    int vg  = t >> 6;                     // wave id: faces f0+vg*2, f0+vg*2+1
    int p4  = t & 63;                     // channel-quad
    int bc0 = p4 * 4;

    // read indices from LDS (broadcast), issue ALL 18 gathers first
    u16x4 xr[2][9];
    #pragma unroll
    for (int i = 0; i < 2; ++i) {
        int fl = vg * 2 + i;
        #pragma unroll
        for (int e = 0; e < 9; ++e) {
            int d = e / 3, j = e - d * 3;
            int col = sGc[d][fl * 3 + j];
            xr[i][e] = *(const u16x4*)&xt[(size_t)col * BC + bc0];
        }
    }
    #pragma unroll
    for (int i = 0; i < 2; ++i) {
        int fl = vg * 2 + i;
        float aew[4] = {0.f, 0.f, 0.f, 0.f}, ans[4] = {0.f, 0.f, 0.f, 0.f};
        #pragma unroll
        for (int d = 0; d < 3; ++d) {
            float g[4] = {0.f, 0.f, 0.f, 0.f};
            #pragma unroll
            for (int j = 0; j < 3; ++j) {
                float val = sGv[d][fl * 3 + j];
                #pragma unroll
                for (int k = 0; k < 4; ++k) g[k] += val * bf2f(xr[i][d * 3 + j][k]);
            }
            float ewd = sEW[fl * 3 + d], nsd = sNS[fl * 3 + d];
            #pragma unroll
            for (int k = 0; k < 4; ++k) {
                aew[k] += ewd * g[k];
                ans[k] += nsd * g[k];
            }
        }
        u16x8 o;
        o[0] = f2bf(aew[0]); o[1] = f2bf(aew[1]); o[2] = f2bf(ans[0]); o[3] = f2bf(ans[1]);
        o[4] = f2bf(aew[2]); o[5] = f2bf(aew[3]); o[6] = f2bf(ans[2]); o[7] = f2bf(ans[3]);
        *(u16x8*)&gfi[(size_t)(f0 + fl) * 512 + p4 * 8] = o;
    }
}

// ---------------- Kernel C: per 8-vertex tile, all batches+channels per block.
// L/F indices+weights staged cooperatively through LDS (1 coalesced load/block);
// both vertices' 28 gathers issued before any accumulate (2x MLP depth).
#define VT 8
#define FROW 136            // fp16 per feat row: 128 ck + 8 pad (272 B)
#define FBP  (16 * FROW)    // one batch-pair tile: 16 rows

__global__ __launch_bounds__(256, 4) void k_vertices(const u16* __restrict__ xt,
                                                  const int* __restrict__ Lc,
                                                  const float* __restrict__ Lv,
                                                  const int* __restrict__ Fc,
                                                  const float* __restrict__ Fv,
                                                  const u16* __restrict__ gfi,
                                                  const float* __restrict__ coeffs,
                                                  float* __restrict__ out) {
    __shared__ _Float16 fh[4 * FBP];   // 17408 B
    __shared__ int   idxL[VT * 7];     // +832 B index/weight staging
    __shared__ float wL[VT * 7];
    __shared__ int   idxF[VT * 6];
    __shared__ float wF[VT * 6];
    int t = threadIdx.x;

    // ---- bijective XCD-aware swizzle (nwg = 5121, not %8==0 -> m204 form)
    const int nwg = (NV + VT - 1) / VT;
    const int q = nwg >> 3, r = nwg & 7;
    int orig = blockIdx.x;
    int xcd = orig & 7, lid = orig >> 3;
    int swz = (xcd < r ? xcd * (q + 1) : r * (q + 1) + (xcd - r) * q) + lid;
    int v0 = swz * VT;

    // ---- phase 0: cooperative index/weight staging (coalesced, once per block)
    if (t < VT * 7) {
        int gi = 7 * v0 + t;
        bool ok = gi < 7 * NV;
        idxL[t] = ok ? Lc[gi] : 0;
        wL[t]   = ok ? Lv[gi] : 0.f;
    } else if (t >= 64 && t < 64 + VT * 6) {
        int gi = 6 * v0 + (t - 64);
        bool ok = gi < 6 * NV;
        idxF[t - 64] = ok ? Fc[gi] : 0;
        wF[t - 64]   = ok ? Fv[gi] : 0.f;
    }
    __syncthreads();

    // ---- phase 1: gather. thread = (bc-quad p4, wave vg); wave owns 2 vertices.
    int p4 = t & 63;          // b = p4>>3, c4 = p4&7
    int vg = t >> 6;          // wave id 0..3
    int b  = p4 >> 3;
    int c4 = p4 & 7;
    int bc0 = p4 * 4;
    int bp = b >> 1;
    int rbase = (b & 1) * 8;
    int bkey = (b & 3) << 4;  // LDS byte-XOR key

    // read this wave's indices from LDS (broadcast), issue ALL 28 gathers
    int lc[2][7], fc[2][6];
    #pragma unroll
    for (int i = 0; i < 2; ++i) {
        int vl = vg * 2 + i;
        #pragma unroll
        for (int j = 0; j < 7; ++j) lc[i][j] = idxL[vl * 7 + j];
        #pragma unroll
        for (int j = 0; j < 6; ++j) fc[i][j] = idxF[vl * 6 + j];
    }
    u16x4 xv[2];
    u16x4 lt[2][7];
    u16x8 ft[2][6];
    #pragma unroll
    for (int i = 0; i < 2; ++i) {
        int v = v0 + vg * 2 + i;
        int vs = v < NV ? v : 0;
        xv[i] = *(const u16x4*)&xt[(size_t)vs * BC + bc0];
        #pragma unroll
        for (int j = 0; j < 7; ++j)
            lt[i][j] = *(const u16x4*)&xt[(size_t)lc[i][j] * BC + bc0];
        #pragma unroll
        for (int j = 0; j < 6; ++j)
            ft[i][j] = *(const u16x8*)&gfi[(size_t)fc[i][j] * 512 + p4 * 8];
    }
    // accumulate + pack + LDS write, per vertex
    #pragma unroll
    for (int i = 0; i < 2; ++i) {
        int vloc = vg * 2 + i;
        int v = v0 + vloc;
        float valid = (v < NV) ? 1.f : 0.f;
        float id[4], lp[4] = {0.f,0.f,0.f,0.f};
        float ew[4] = {0.f,0.f,0.f,0.f}, ns[4] = {0.f,0.f,0.f,0.f};
        #pragma unroll
        for (int k = 0; k < 4; ++k) id[k] = valid * bf2f(xv[i][k]);
        #pragma unroll
        for (int j = 0; j < 7; ++j) {
            float val = wL[vloc * 7 + j];
            #pragma unroll
            for (int k = 0; k < 4; ++k) lp[k] += val * bf2f(lt[i][j][k]);
        }
        #pragma unroll
        for (int j = 0; j < 6; ++j) {
            float val = wF[vloc * 6 + j];
            ew[0] += val * bf2f(ft[i][j][0]);  ew[1] += val * bf2f(ft[i][j][1]);
            ns[0] += val * bf2f(ft[i][j][2]);  ns[1] += val * bf2f(ft[i][j][3]);
            ew[2] += val * bf2f(ft[i][j][4]);  ew[3] += val * bf2f(ft[i][j][5]);
            ns[2] += val * bf2f(ft[i][j][6]);  ns[3] += val * bf2f(ft[i][j][7]);
        }
        int rowsh = bp * FBP + (rbase + vloc) * FROW;
        f16x8 h0, h1;
        h0[0]=(_Float16)id[0]; h0[1]=(_Float16)lp[0]; h0[2]=(_Float16)ew[0]; h0[3]=(_Float16)ns[0];
        h0[4]=(_Float16)id[1]; h0[5]=(_Float16)lp[1]; h0[6]=(_Float16)ew[1]; h0[7]=(_Float16)ns[1];
        h1[0]=(_Float16)id[2]; h1[1]=(_Float16)lp[2]; h1[2]=(_Float16)ew[2]; h1[3]=(_Float16)ns[2];
        h1[4]=(_Float16)id[3]; h1[5]=(_Float16)lp[3]; h1[6]=(_Float16)ew[3]; h1[7]=(_Float16)ns[3];
        *(f16x8*)&fh[rowsh + (((c4 * 32)      ^ bkey) >> 1)] = h0;
        *(f16x8*)&fh[rowsh + (((c4 * 32 + 16) ^ bkey) >> 1)] = h1;
    }

    // ---- B fragments (coeffs 128x64 f32, L2-hit): hi/lo fp16 split
    int w  = vg;              // wave -> o-tile (w*16)
    int l  = t & 63;
    int lr = l & 15;          // o within tile / A-row
    int lq = l >> 4;          // k-octet select
    f16x8 Bh[4], Bl[4];
    #pragma unroll
    for (int ks = 0; ks < 4; ++ks) {
        #pragma unroll
        for (int e = 0; e < 8; ++e) {
            int k = ks * 32 + lq * 8 + e;
            float c = coeffs[k * 64 + w * 16 + lr];
            _Float16 h = (_Float16)c;
            Bh[ks][e] = h;
            Bl[ks][e] = (_Float16)(c - (float)h);
        }
    }
    __syncthreads();

    // ---- phase 2: per wave one 16-o tile; loop 4 batch-pairs; K=128 in 4 steps.
    #pragma unroll
    for (int bp2 = 0; bp2 < 4; ++bp2) {
        int akey = ((bp2 * 2 + (lr >> 3)) & 3) << 4;   // matches writer's b&3 key
        f32x4 acc = {0.f, 0.f, 0.f, 0.f};
        #pragma unroll
        for (int ks = 0; ks < 4; ++ks) {
            int byteoff = (ks * 64 + lq * 16) ^ akey;
            f16x8 A = *(const f16x8*)&fh[bp2 * FBP + lr * FROW + (byteoff >> 1)];
            acc = __builtin_amdgcn_mfma_f32_16x16x32_f16(A, Bh[ks], acc, 0, 0, 0);
            acc = __builtin_amdgcn_mfma_f32_16x16x32_f16(A, Bl[ks], acc, 0, 0, 0);
        }
        // C layout: col = lane&15 (o), rows = lq*4 + j
        int r0 = lq * 4;
        int bb = bp2 * 2 + (r0 >> 3);
        int vbase = v0 + (r0 & 7);
        int o = w * 16 + lr;
        size_t off = ((size_t)(bb * 64 + o)) * NV + vbase;
        if (v0 + VT <= NV) {
            *(float2*)&out[off]     = make_float2(acc.x, acc.y);
            *(float2*)&out[off + 2] = make_float2(acc.z, acc.w);
        } else {
            #pragma unroll
            for (int j = 0; j < 4; ++j)
                if (vbase + j < NV) out[off + j] = acc[j];
        }
    }
}

extern "C" void kernel_launch(void* const* d_in, const int* in_sizes, int n_in,
                              void* d_out, int out_size, void* d_ws, size_t ws_size,
                              hipStream_t stream) {
    (void)in_sizes; (void)n_in; (void)out_size; (void)ws_size;
    const float* input = (const float*)d_in[0];
    const int*   Gc = (const int*)d_in[2];
    const float* Gv = (const float*)d_in[3];
    const int*   Lc = (const int*)d_in[5];
    const float* Lv = (const float*)d_in[6];
    const int*   Fc = (const int*)d_in[8];
    const float* Fv = (const float*)d_in[9];
    const float* EW = (const float*)d_in[10];
    const float* NS = (const float*)d_in[11];
    const float* coeffs = (const float*)d_in[12];
    float* out = (float*)d_out;

    u16* ws  = (u16*)d_ws;
    u16* xt  = ws;                       // NV*256 bf16
    u16* gfi = ws + (size_t)NV * BC;     // NF*512 bf16 (ew/ns interleaved)

    dim3 gA((NV + 31) / 32, BC / 32);
    k_transpose<<<gA, 256, 0, stream>>>(input, xt);

    k_faces<<<dim3(NF / 8), 256, 0, stream>>>(xt, Gc, Gv, EW, NS, gfi);

    k_vertices<<<dim3((NV + VT - 1) / VT), 256, 0, stream>>>(
        xt, Lc, Lv, Fc, Fv, gfi, coeffs, out);
}

// Round 6
// 148.196 us; speedup vs baseline: 1.0530x; 1.0530x over previous
//
#include <hip/hip_runtime.h>

#define NV 40962
#define NF 81920
#define BSZ 8
#define CIN 32
#define COUT 64
#define BC 256   // BSZ*CIN

typedef unsigned short u16;
typedef float    f32x4 __attribute__((ext_vector_type(4)));
typedef _Float16 f16x8 __attribute__((ext_vector_type(8)));
typedef unsigned short u16x4 __attribute__((ext_vector_type(4)));
typedef unsigned short u16x8 __attribute__((ext_vector_type(8)));

__device__ __forceinline__ float bf2f(u16 h) {
    return __uint_as_float(((unsigned int)h) << 16);
}
__device__ __forceinline__ u16 f2bf(float f) {
    unsigned int u = __float_as_uint(f);
    unsigned int r = (u + 0x7fffu + ((u >> 16) & 1u)) >> 16;
    return (u16)r;
}

// Inline-asm gathers: compiler cannot sink these past each other or the
// s_waitcnt, so all loads in a burst stay in flight together (deep MLP).
__device__ __forceinline__ uint2 gload8(const u16* base, int voff) {
    uint2 d;
    asm volatile("global_load_dwordx2 %0, %1, %2"
                 : "=v"(d) : "v"(voff), "s"(base));
    return d;
}
__device__ __forceinline__ uint4 gload16(const u16* base, int voff) {
    uint4 d;
    asm volatile("global_load_dwordx4 %0, %1, %2"
                 : "=v"(d) : "v"(voff), "s"(base));
    return d;
}
__device__ __forceinline__ void gwait0() {
    asm volatile("s_waitcnt vmcnt(0)" ::: "memory");
    __builtin_amdgcn_sched_barrier(0);   // rule 18: keep consumers below the wait
}

// ---------------- Kernel A: transpose input (256 x NV f32) -> xt (NV x 256 bf16)
__global__ __launch_bounds__(256) void k_transpose(const float* __restrict__ in,
                                                   u16* __restrict__ xt) {
    __shared__ float tile[32][33];   // [bc_local][v_local]
    int c0 = blockIdx.x * 32;   // v-dim tile start
    int r0 = blockIdx.y * 32;   // bc-dim tile start
    int tx = threadIdx.x & 31;
    int ty = threadIdx.x >> 5;  // 0..7
    #pragma unroll
    for (int i = 0; i < 32; i += 8) {
        int cc = c0 + tx;
        float v = 0.f;
        if (cc < NV) v = in[(size_t)(r0 + ty + i) * NV + cc];
        tile[ty + i][tx] = v;
    }
    __syncthreads();
    int t = threadIdx.x;
    #pragma unroll
    for (int e = t; e < 512; e += 256) {
        int vl = e >> 4;          // 0..31 (v_local)
        int p  = e & 15;          // channel pair
        int v  = c0 + vl;
        if (v < NV) {
            ushort2 val;
            val.x = f2bf(tile[p * 2][vl]);
            val.y = f2bf(tile[p * 2 + 1][vl]);
            *(ushort2*)&xt[(size_t)v * BC + r0 + p * 2] = val;
        }
    }
}

// ---------------- Kernel B: 8 faces/block, 2 faces/wave; G/EW/NS staged in LDS;
// 18 asm-issued gathers in flight per wave.
// gfi layout: [f][C2][4] = {ew_lo, ew_hi, ns_lo, ns_hi} per channel-pair.
__global__ __launch_bounds__(256) void k_faces(const u16* __restrict__ xt,
                                               const int* __restrict__ Gc,
                                               const float* __restrict__ Gv,
                                               const float* __restrict__ EW,
                                               const float* __restrict__ NS,
                                               u16* __restrict__ gfi) {
    __shared__ int   sGc[3][24];
    __shared__ float sGv[3][24];
    __shared__ float sEW[24];
    __shared__ float sNS[24];
    int t  = threadIdx.x;
    int f0 = blockIdx.x * 8;              // NF/8 = 10240 blocks, no tail

    if (t < 24) {
        #pragma unroll
        for (int d = 0; d < 3; ++d) {
            sGc[d][t] = Gc[3 * (d * NF + f0) + t];
            sGv[d][t] = Gv[3 * (d * NF + f0) + t];
        }
    } else if (t >= 32 && t < 56) {
        sEW[t - 32] = EW[f0 * 3 + (t - 32)];
        sNS[t - 32] = NS[f0 * 3 + (t - 32)];
    }
    __syncthreads();

    int vg  = t >> 6;                     // wave id: faces f0+vg*2, f0+vg*2+1
    int p4  = t & 63;                     // channel-quad
    int po  = p4 << 3;                    // byte offset within a 512 B row

    // indices from LDS (broadcast), then issue ALL 18 gathers back-to-back
    int gcol[2][9];
    #pragma unroll
    for (int i = 0; i < 2; ++i) {
        int fl = vg * 2 + i;
        #pragma unroll
        for (int e = 0; e < 9; ++e) {
            int d = e / 3, j = e - d * 3;
            gcol[i][e] = sGc[d][fl * 3 + j];
        }
    }
    uint2 xr[2][9];
    #pragma unroll
    for (int i = 0; i < 2; ++i)
        #pragma unroll
        for (int e = 0; e < 9; ++e)
            xr[i][e] = gload8(xt, (gcol[i][e] << 9) + po);
    gwait0();

    #pragma unroll
    for (int i = 0; i < 2; ++i) {
        int fl = vg * 2 + i;
        float aew[4] = {0.f, 0.f, 0.f, 0.f}, ans[4] = {0.f, 0.f, 0.f, 0.f};
        #pragma unroll
        for (int d = 0; d < 3; ++d) {
            float g[4] = {0.f, 0.f, 0.f, 0.f};
            #pragma unroll
            for (int j = 0; j < 3; ++j) {
                float val = sGv[d][fl * 3 + j];
                u16x4 x = __builtin_bit_cast(u16x4, xr[i][d * 3 + j]);
                #pragma unroll
                for (int k = 0; k < 4; ++k) g[k] += val * bf2f(x[k]);
            }
            float ewd = sEW[fl * 3 + d], nsd = sNS[fl * 3 + d];
            #pragma unroll
            for (int k = 0; k < 4; ++k) {
                aew[k] += ewd * g[k];
                ans[k] += nsd * g[k];
            }
        }
        u16x8 o;
        o[0] = f2bf(aew[0]); o[1] = f2bf(aew[1]); o[2] = f2bf(ans[0]); o[3] = f2bf(ans[1]);
        o[4] = f2bf(aew[2]); o[5] = f2bf(aew[3]); o[6] = f2bf(ans[2]); o[7] = f2bf(ans[3]);
        *(u16x8*)&gfi[(size_t)(f0 + fl) * 512 + p4 * 8] = o;
    }
}

// ---------------- Kernel C: per 8-vertex tile, all batches+channels per block.
// Indices staged in LDS; 28 asm-issued gathers in flight per wave (2 vertices),
// one vmcnt(0) drain, then accumulate. MFMA epilogue unchanged.
#define VT 8
#define FROW 136            // fp16 per feat row: 128 ck + 8 pad (272 B)
#define FBP  (16 * FROW)    // one batch-pair tile: 16 rows

__global__ __launch_bounds__(256, 4) void k_vertices(const u16* __restrict__ xt,
                                                  const int* __restrict__ Lc,
                                                  const float* __restrict__ Lv,
                                                  const int* __restrict__ Fc,
                                                  const float* __restrict__ Fv,
                                                  const u16* __restrict__ gfi,
                                                  const float* __restrict__ coeffs,
                                                  float* __restrict__ out) {
    __shared__ _Float16 fh[4 * FBP];   // 17408 B
    __shared__ int   idxL[VT * 7];     // +832 B index/weight staging
    __shared__ float wL[VT * 7];
    __shared__ int   idxF[VT * 6];
    __shared__ float wF[VT * 6];
    int t = threadIdx.x;

    // ---- bijective XCD-aware swizzle (nwg = 5121, not %8==0 -> m204 form)
    const int nwg = (NV + VT - 1) / VT;
    const int q = nwg >> 3, r = nwg & 7;
    int orig = blockIdx.x;
    int xcd = orig & 7, lid = orig >> 3;
    int swz = (xcd < r ? xcd * (q + 1) : r * (q + 1) + (xcd - r) * q) + lid;
    int v0 = swz * VT;

    // ---- phase 0: cooperative index/weight staging (coalesced, once per block)
    if (t < VT * 7) {
        int gi = 7 * v0 + t;
        bool ok = gi < 7 * NV;
        idxL[t] = ok ? Lc[gi] : 0;
        wL[t]   = ok ? Lv[gi] : 0.f;
    } else if (t >= 64 && t < 64 + VT * 6) {
        int gi = 6 * v0 + (t - 64);
        bool ok = gi < 6 * NV;
        idxF[t - 64] = ok ? Fc[gi] : 0;
        wF[t - 64]   = ok ? Fv[gi] : 0.f;
    }
    __syncthreads();

    // ---- phase 1: gather. thread = (bc-quad p4, wave vg); wave owns 2 vertices.
    int p4 = t & 63;          // b = p4>>3, c4 = p4&7
    int vg = t >> 6;          // wave id 0..3
    int b  = p4 >> 3;
    int c4 = p4 & 7;
    int bp = b >> 1;
    int rbase = (b & 1) * 8;
    int bkey = (b & 3) << 4;  // LDS byte-XOR key
    int po8  = p4 << 3;       // byte offset in 512 B row
    int po16 = p4 << 4;       // byte offset in 1024 B row

    // indices from LDS (all lgkm waits complete before the issue burst)
    int lc[2][7], fc[2][6], vsv[2];
    #pragma unroll
    for (int i = 0; i < 2; ++i) {
        int vl = vg * 2 + i;
        int v  = v0 + vl;
        vsv[i] = v < NV ? v : 0;
        #pragma unroll
        for (int j = 0; j < 7; ++j) lc[i][j] = idxL[vl * 7 + j];
        #pragma unroll
        for (int j = 0; j < 6; ++j) fc[i][j] = idxF[vl * 6 + j];
    }
    // ---- issue ALL 28 gathers back-to-back (volatile asm: cannot be sunk)
    uint2 xv[2];
    uint2 lt[2][7];
    uint4 ft[2][6];
    #pragma unroll
    for (int i = 0; i < 2; ++i) {
        xv[i] = gload8(xt, (vsv[i] << 9) + po8);
        #pragma unroll
        for (int j = 0; j < 7; ++j)
            lt[i][j] = gload8(xt, (lc[i][j] << 9) + po8);
    }
    #pragma unroll
    for (int i = 0; i < 2; ++i)
        #pragma unroll
        for (int j = 0; j < 6; ++j)
            ft[i][j] = gload16(gfi, (fc[i][j] << 10) + po16);
    gwait0();

    // ---- accumulate + pack + LDS write, per vertex
    #pragma unroll
    for (int i = 0; i < 2; ++i) {
        int vloc = vg * 2 + i;
        int v = v0 + vloc;
        float valid = (v < NV) ? 1.f : 0.f;
        float id[4], lp[4] = {0.f,0.f,0.f,0.f};
        float ew[4] = {0.f,0.f,0.f,0.f}, ns[4] = {0.f,0.f,0.f,0.f};
        u16x4 xvv = __builtin_bit_cast(u16x4, xv[i]);
        #pragma unroll
        for (int k = 0; k < 4; ++k) id[k] = valid * bf2f(xvv[k]);
        #pragma unroll
        for (int j = 0; j < 7; ++j) {
            float val = wL[vloc * 7 + j];
            u16x4 x = __builtin_bit_cast(u16x4, lt[i][j]);
            #pragma unroll
            for (int k = 0; k < 4; ++k) lp[k] += val * bf2f(x[k]);
        }
        #pragma unroll
        for (int j = 0; j < 6; ++j) {
            float val = wF[vloc * 6 + j];
            u16x8 x = __builtin_bit_cast(u16x8, ft[i][j]);
            ew[0] += val * bf2f(x[0]);  ew[1] += val * bf2f(x[1]);
            ns[0] += val * bf2f(x[2]);  ns[1] += val * bf2f(x[3]);
            ew[2] += val * bf2f(x[4]);  ew[3] += val * bf2f(x[5]);
            ns[2] += val * bf2f(x[6]);  ns[3] += val * bf2f(x[7]);
        }
        int rowsh = bp * FBP + (rbase + vloc) * FROW;
        f16x8 h0, h1;
        h0[0]=(_Float16)id[0]; h0[1]=(_Float16)lp[0]; h0[2]=(_Float16)ew[0]; h0[3]=(_Float16)ns[0];
        h0[4]=(_Float16)id[1]; h0[5]=(_Float16)lp[1]; h0[6]=(_Float16)ew[1]; h0[7]=(_Float16)ns[1];
        h1[0]=(_Float16)id[2]; h1[1]=(_Float16)lp[2]; h1[2]=(_Float16)ew[2]; h1[3]=(_Float16)ns[2];
        h1[4]=(_Float16)id[3]; h1[5]=(_Float16)lp[3]; h1[6]=(_Float16)ew[3]; h1[7]=(_Float16)ns[3];
        *(f16x8*)&fh[rowsh + (((c4 * 32)      ^ bkey) >> 1)] = h0;
        *(f16x8*)&fh[rowsh + (((c4 * 32 + 16) ^ bkey) >> 1)] = h1;
    }

    // ---- B fragments (coeffs 128x64 f32, L2-hit): hi/lo fp16 split
    int w  = vg;              // wave -> o-tile (w*16)
    int l  = t & 63;
    int lr = l & 15;          // o within tile / A-row
    int lq = l >> 4;          // k-octet select
    f16x8 Bh[4], Bl[4];
    #pragma unroll
    for (int ks = 0; ks < 4; ++ks) {
        #pragma unroll
        for (int e = 0; e < 8; ++e) {
            int k = ks * 32 + lq * 8 + e;
            float c = coeffs[k * 64 + w * 16 + lr];
            _Float16 h = (_Float16)c;
            Bh[ks][e] = h;
            Bl[ks][e] = (_Float16)(c - (float)h);
        }
    }
    __syncthreads();

    // ---- phase 2: per wave one 16-o tile; loop 4 batch-pairs; K=128 in 4 steps.
    #pragma unroll
    for (int bp2 = 0; bp2 < 4; ++bp2) {
        int akey = ((bp2 * 2 + (lr >> 3)) & 3) << 4;   // matches writer's b&3 key
        f32x4 acc = {0.f, 0.f, 0.f, 0.f};
        #pragma unroll
        for (int ks = 0; ks < 4; ++ks) {
            int byteoff = (ks * 64 + lq * 16) ^ akey;
            f16x8 A = *(const f16x8*)&fh[bp2 * FBP + lr * FROW + (byteoff >> 1)];
            acc = __builtin_amdgcn_mfma_f32_16x16x32_f16(A, Bh[ks], acc, 0, 0, 0);
            acc = __builtin_amdgcn_mfma_f32_16x16x32_f16(A, Bl[ks], acc, 0, 0, 0);
        }
        // C layout: col = lane&15 (o), rows = lq*4 + j
        int r0 = lq * 4;
        int bb = bp2 * 2 + (r0 >> 3);
        int vbase = v0 + (r0 & 7);
        int o = w * 16 + lr;
        size_t off = ((size_t)(bb * 64 + o)) * NV + vbase;
        if (v0 + VT <= NV) {
            *(float2*)&out[off]     = make_float2(acc.x, acc.y);
            *(float2*)&out[off + 2] = make_float2(acc.z, acc.w);
        } else {
            #pragma unroll
            for (int j = 0; j < 4; ++j)
                if (vbase + j < NV) out[off + j] = acc[j];
        }
    }
}

extern "C" void kernel_launch(void* const* d_in, const int* in_sizes, int n_in,
                              void* d_out, int out_size, void* d_ws, size_t ws_size,
                              hipStream_t stream) {
    (void)in_sizes; (void)n_in; (void)out_size; (void)ws_size;
    const float* input = (const float*)d_in[0];
    const int*   Gc = (const int*)d_in[2];
    const float* Gv = (const float*)d_in[3];
    const int*   Lc = (const int*)d_in[5];
    const float* Lv = (const float*)d_in[6];
    const int*   Fc = (const int*)d_in[8];
    const float* Fv = (const float*)d_in[9];
    const float* EW = (const float*)d_in[10];
    const float* NS = (const float*)d_in[11];
    const float* coeffs = (const float*)d_in[12];
    float* out = (float*)d_out;

    u16* ws  = (u16*)d_ws;
    u16* xt  = ws;                       // NV*256 bf16
    u16* gfi = ws + (size_t)NV * BC;     // NF*512 bf16 (ew/ns interleaved)

    dim3 gA((NV + 31) / 32, BC / 32);
    k_transpose<<<gA, 256, 0, stream>>>(input, xt);

    k_faces<<<dim3(NF / 8), 256, 0, stream>>>(xt, Gc, Gv, EW, NS, gfi);

    k_vertices<<<dim3((NV + VT - 1) / VT), 256, 0, stream>>>(
        xt, Lc, Lv, Fc, Fv, gfi, coeffs, out);
}